// Round 2
// baseline (316.226 us; speedup 1.0000x reference)
//
#include <hip/hip_runtime.h>
#include <stdint.h>

// HashEmbedder (Instant-NGP hash grid), MI355X gfx950.
// R1 -> R2: compiler had register-minimized the unrolled loop to ~8 outstanding
// gathers/wave (VGPR=36, latency-bound at 2 cyc/request vs ~1 cyc/req TA floor).
// Restructure: compute all 64 indices + issue all 64 float2 gathers first
// (sched_barrier(0) pins the phase boundary), then do all interpolation.
// Trades occupancy (~65%->~37%) for 4x memory-level parallelism per wave.

#define TABLE_SIZE (1u << 19)
#define TMASK (TABLE_SIZE - 1u)
#define P2 2654435761u
#define P3 805459861u

__global__ __launch_bounds__(256) void hash_embed_kernel(
    const float* __restrict__ x, const float* __restrict__ tables,
    float* __restrict__ out, int n)
{
    const int i = blockIdx.x * 256 + threadIdx.x;
    if (i >= n) return;

    const float px = x[3 * i + 0];
    const float py = x[3 * i + 1];
    const float pz = x[3 * i + 2];
    const float cx = fminf(fmaxf(px, 0.0f), 1.0f);
    const float cy = fminf(fmaxf(py, 0.0f), 1.0f);
    const float cz = fminf(fmaxf(pz, 0.0f), 1.0f);

    const float resf[8] = {16.f, 20.f, 25.f, 32.f, 40.f, 50.f, 64.f, 80.f};

    float2 e[8][8];            // 128 VGPRs of gathered embeddings
    float wxa[8], wya[8], wza[8];

    // ---- phase 1: all address math + all 64 gathers issued back-to-back ----
#pragma unroll
    for (int l = 0; l < 8; ++l) {
        const float R = resf[l];
        const float g = 1.0f / R;

        const int bx = (int)floorf(cx * R);
        const int by = (int)floorf(cy * R);
        const int bz = (int)floorf(cz * R);

        wxa[l] = (px - (float)bx * g) * R;
        wya[l] = (py - (float)by * g) * R;
        wza[l] = (pz - (float)bz * g) * R;

        const uint32_t hx0 = (uint32_t)bx;          // prime for dim0 is 1
        const uint32_t hx1 = hx0 + 1u;
        const uint32_t hy0 = (uint32_t)by * P2;
        const uint32_t hy1 = hy0 + P2;
        const uint32_t hz0 = (uint32_t)bz * P3;
        const uint32_t hz1 = hz0 + P3;

        const float2* __restrict__ tab =
            (const float2*)(tables) + (size_t)l * (size_t)TABLE_SIZE;

        e[l][0] = tab[(hx0 ^ hy0 ^ hz0) & TMASK];
        e[l][1] = tab[(hx0 ^ hy0 ^ hz1) & TMASK];
        e[l][2] = tab[(hx0 ^ hy1 ^ hz0) & TMASK];
        e[l][3] = tab[(hx0 ^ hy1 ^ hz1) & TMASK];
        e[l][4] = tab[(hx1 ^ hy0 ^ hz0) & TMASK];
        e[l][5] = tab[(hx1 ^ hy0 ^ hz1) & TMASK];
        e[l][6] = tab[(hx1 ^ hy1 ^ hz0) & TMASK];
        e[l][7] = tab[(hx1 ^ hy1 ^ hz1) & TMASK];
    }

    // Pin the schedule: no interp hoisted above, no load sunk below.
    __builtin_amdgcn_sched_barrier(0);

    // ---- phase 2: trilinear interpolation, level by level ----
    float o[16];
#pragma unroll
    for (int l = 0; l < 8; ++l) {
        const float wx = wxa[l], wy = wya[l], wz = wza[l];
        const float omx = 1.0f - wx, omy = 1.0f - wy, omz = 1.0f - wz;

        const float c00a = e[l][0].x * omx + e[l][4].x * wx;
        const float c00b = e[l][0].y * omx + e[l][4].y * wx;
        const float c01a = e[l][1].x * omx + e[l][5].x * wx;
        const float c01b = e[l][1].y * omx + e[l][5].y * wx;
        const float c10a = e[l][2].x * omx + e[l][6].x * wx;
        const float c10b = e[l][2].y * omx + e[l][6].y * wx;
        const float c11a = e[l][3].x * omx + e[l][7].x * wx;
        const float c11b = e[l][3].y * omx + e[l][7].y * wx;

        const float c0a = c00a * omy + c10a * wy;
        const float c0b = c00b * omy + c10b * wy;
        const float c1a = c01a * omy + c11a * wy;
        const float c1b = c01b * omy + c11b * wy;

        o[2 * l + 0] = c0a * omz + c1a * wz;
        o[2 * l + 1] = c0b * omz + c1b * wz;
    }

    float4* __restrict__ op = (float4*)(out + (size_t)i * 16);
    op[0] = make_float4(o[0], o[1], o[2], o[3]);
    op[1] = make_float4(o[4], o[5], o[6], o[7]);
    op[2] = make_float4(o[8], o[9], o[10], o[11]);
    op[3] = make_float4(o[12], o[13], o[14], o[15]);
}

extern "C" void kernel_launch(void* const* d_in, const int* in_sizes, int n_in,
                              void* d_out, int out_size, void* d_ws, size_t ws_size,
                              hipStream_t stream) {
    const float* x = (const float*)d_in[0];
    const float* tables = (const float*)d_in[1];
    float* out = (float*)d_out;
    const int n = in_sizes[0] / 3;  // 1048576 points
    const int block = 256;
    const int grid = (n + block - 1) / block;
    hash_embed_kernel<<<grid, block, 0, stream>>>(x, tables, out, n);
}